// Round 10
// baseline (191.974 us; speedup 1.0000x reference)
//
#include <hip/hip_runtime.h>
#include <math.h>

#define BB 4
#define NN 4096
#define CC 1024
#define HH 16
#define HD 64
#define LM 64
#define SEG 64
#define BHN (BB*HH)          // 64
#define MATP 68              // fp32 row stride (inv buffers + Prow)
#define MATE (64*MATP)
#define NTILE 32             // k3v grid.x
#define APROW 4352           // 4096 acc + 4*64 per-wave srow partials

typedef __attribute__((ext_vector_type(8))) short bf16x8;
typedef __attribute__((ext_vector_type(4))) short s16x4;
typedef __attribute__((ext_vector_type(4))) float f32x4;
typedef __attribute__((ext_vector_type(4))) unsigned u32x4;

__device__ __forceinline__ float shfl_sum16(float v) {
  v += __shfl_xor(v, 1, 16);
  v += __shfl_xor(v, 2, 16);
  v += __shfl_xor(v, 4, 16);
  v += __shfl_xor(v, 8, 16);
  return v;
}

// split fp32 -> bf16 hi (chop) + bf16 lo (chop of residual); rel err ~2^-16
__device__ __forceinline__ void split8(const float* f, bf16x8& hi, bf16x8& lo) {
#pragma unroll
  for (int i = 0; i < 8; ++i) {
    unsigned u = __builtin_bit_cast(unsigned, f[i]);
    float hf = __builtin_bit_cast(float, u & 0xFFFF0000u);
    hi[i] = (short)(u >> 16);
    float l = f[i] - hf;
    unsigned ul = __builtin_bit_cast(unsigned, l);
    lo[i] = (short)(ul >> 16);
  }
}

__device__ __forceinline__ void split4(const float* f, s16x4& hi, s16x4& lo) {
#pragma unroll
  for (int i = 0; i < 4; ++i) {
    unsigned u = __builtin_bit_cast(unsigned, f[i]);
    float hf = __builtin_bit_cast(float, u & 0xFFFF0000u);
    hi[i] = (short)(u >> 16);
    float l = f[i] - hf;
    unsigned ul = __builtin_bit_cast(unsigned, l);
    lo[i] = (short)(ul >> 16);
  }
}

// pack 4 floats -> 2 u32 of bf16-hi pairs + 2 u32 of bf16-lo pairs
__device__ __forceinline__ void packsplit4(const float e[4],
    unsigned& h01, unsigned& h23, unsigned& l01, unsigned& l23) {
  unsigned u0 = __builtin_bit_cast(unsigned, e[0]);
  unsigned u1 = __builtin_bit_cast(unsigned, e[1]);
  unsigned u2 = __builtin_bit_cast(unsigned, e[2]);
  unsigned u3 = __builtin_bit_cast(unsigned, e[3]);
  h01 = (u0 >> 16) | (u1 & 0xFFFF0000u);
  h23 = (u2 >> 16) | (u3 & 0xFFFF0000u);
  float r0 = e[0] - __builtin_bit_cast(float, u0 & 0xFFFF0000u);
  float r1 = e[1] - __builtin_bit_cast(float, u1 & 0xFFFF0000u);
  float r2 = e[2] - __builtin_bit_cast(float, u2 & 0xFFFF0000u);
  float r3 = e[3] - __builtin_bit_cast(float, u3 & 0xFFFF0000u);
  l01 = (__builtin_bit_cast(unsigned, r0) >> 16) | (__builtin_bit_cast(unsigned, r1) & 0xFFFF0000u);
  l23 = (__builtin_bit_cast(unsigned, r2) >> 16) | (__builtin_bit_cast(unsigned, r3) & 0xFFFF0000u);
}

__device__ __forceinline__ bf16x8 mk8(unsigned w0, unsigned w1, unsigned w2, unsigned w3) {
  u32x4 u = (u32x4){w0, w1, w2, w3};
  return __builtin_bit_cast(bf16x8, u);
}

// m214-style plane: 64 rows x 64 shorts (128B rows), byte ^= (row&7)<<4.
__device__ __forceinline__ int planeAddr(int row, int cd) {
  int B = (row << 7) + (cd << 4);
  return B ^ ((row & 7) << 4);
}
__device__ __forceinline__ bf16x8 ldP(const short* __restrict__ P, int row, int cd) {
  return *(const bf16x8*)((const char*)P + planeAddr(row, cd));
}

// in-wave 4x4 transpose among lanes {l, l^16, l^32, l^48}
__device__ __forceinline__ void xpose4(float x[4], int lane) {
  bool p1 = (lane >> 4) & 1;
  float s0 = p1 ? x[0] : x[1], s1 = p1 ? x[2] : x[3];
  float r0 = __shfl_xor(s0, 16, 64), r1 = __shfl_xor(s1, 16, 64);
  if (p1) { x[0] = r0; x[2] = r1; } else { x[1] = r0; x[3] = r1; }
  bool p2 = (lane >> 5) & 1;
  s0 = p2 ? x[0] : x[2]; s1 = p2 ? x[1] : x[3];
  r0 = __shfl_xor(s0, 32, 64); r1 = __shfl_xor(s1, 32, 64);
  if (p2) { x[0] = r0; x[1] = r1; } else { x[2] = r0; x[3] = r1; }
}

// ---------------- Kernel A: landmark means (Q and K) ----------------
__global__ __launch_bounds__(256) void lm_kernel(
    const float* __restrict__ Q, const float* __restrict__ K,
    float* __restrict__ qlm, float* __restrict__ klm) {
  int bh = blockIdx.y; int b = bh >> 4; int h = bh & 15;
  int tid = threadIdx.x;
  int l = blockIdx.x * 4 + (tid >> 6);
  int d = tid & 63;
  const float* qbase = Q + ((size_t)b*NN + (size_t)l*SEG)*CC + h*HD + d;
  const float* kbase = K + ((size_t)b*NN + (size_t)l*SEG)*CC + h*HD + d;
  float sq = 0.f, sk = 0.f;
#pragma unroll 8
  for (int s = 0; s < SEG; ++s) {
    sq += qbase[(size_t)s*CC];
    sk += kbase[(size_t)s*CC];
  }
  qlm[(size_t)bh*4096 + l*64 + d] = sq * (1.0f/(64.0f*8.0f));
  klm[(size_t)bh*4096 + l*64 + d] = sk * (1.0f/64.0f);
}

// ---------------- Kernel B: partials of kernel_3 @ V (swapped Z^T + reg E-frags) ----------------
__global__ __launch_bounds__(256, 3) void k3v_kernel(
    const float* __restrict__ K, const float* __restrict__ V,
    const float* __restrict__ qlm, float* __restrict__ ACC3p) {
  __shared__ alignas(16) char SM[32768];
  short* KEh = (short*)SM;              // K tile [n][d] hi plane (8 KB)
  short* KEl = (short*)(SM + 8192);
  short* VtH = (short*)(SM + 16384);    // V^T [d][n] hi plane
  short* VtL = (short*)(SM + 24576);
  const int bh = blockIdx.y, b = bh >> 4, h = bh & 15;
  const int tile = blockIdx.x, tid = threadIdx.x;
  const int wid = tid >> 6, lane = tid & 63;
  const int lr = lane & 15, lg = lane >> 4;
  const int dV = 4*lr + lg;

  // qlm B-fragments -> registers (rows lt*16+lr, k = d = ks*32+lg*8)
  bf16x8 qbh[4][2], qbl[4][2];
#pragma unroll
  for (int lt = 0; lt < 4; ++lt)
#pragma unroll
    for (int ks = 0; ks < 2; ++ks) {
      const float* qp = qlm + (size_t)bh*4096 + (lt*16 + lr)*64 + ks*32 + lg*8;
      float qf[8];
      *(float4*)&qf[0] = *(const float4*)qp;
      *(float4*)&qf[4] = *(const float4*)(qp + 4);
      split8(qf, qbh[lt][ks], qbl[lt][ks]);
    }

  f32x4 acc2[4][4];   // [dt][lt] partial ACC^T[d][l] over this wave's n-slices
#pragma unroll
  for (int i = 0; i < 4; ++i)
#pragma unroll
    for (int j = 0; j < 4; ++j) acc2[i][j] = (f32x4){0.f, 0.f, 0.f, 0.f};
  float srw[4] = {0.f, 0.f, 0.f, 0.f};

  const int rk0 = tid >> 3, ck = tid & 7;
  const int rk1 = (tid + 256) >> 3;
  float4 gk[2][2], gv[4];

#define K3V_LOAD(SUB)                                                          \
  {                                                                            \
    const int n0_ = tile*128 + (SUB)*64;                                       \
    const float* kb0 = &K[((size_t)b*NN + n0_ + rk0)*CC + h*HD + ck*8];        \
    const float* kb1 = &K[((size_t)b*NN + n0_ + rk1)*CC + h*HD + ck*8];        \
    gk[0][0] = *(const float4*)kb0;  gk[0][1] = *(const float4*)(kb0 + 4);     \
    gk[1][0] = *(const float4*)kb1;  gk[1][1] = *(const float4*)(kb1 + 4);     \
    _Pragma("unroll")                                                          \
    for (int q = 0; q < 4; ++q) {                                              \
      int f = tid + 256*q;                                                     \
      int r = f >> 4, c4 = (f & 15) << 2;                                      \
      gv[q] = *(const float4*)&V[((size_t)b*NN + n0_ + r)*CC + h*HD + c4];     \
    }                                                                          \
  }

#define K3V_WRITE()                                                            \
  {                                                                            \
    _Pragma("unroll")                                                          \
    for (int q2 = 0; q2 < 2; ++q2) {                                           \
      float kf[8];                                                             \
      *(float4*)&kf[0] = gk[q2][0];                                            \
      *(float4*)&kf[4] = gk[q2][1];                                            \
      bf16x8 khv, klv; split8(kf, khv, klv);                                   \
      int r = q2 ? rk1 : rk0;                                                  \
      int A = planeAddr(r, ck);                                                \
      *(bf16x8*)((char*)KEh + A) = khv;                                        \
      *(bf16x8*)((char*)KEl + A) = klv;                                        \
    }                                                                          \
    _Pragma("unroll")                                                          \
    for (int q = 0; q < 4; ++q) {                                              \
      float x[4] = {gv[q].x, gv[q].y, gv[q].z, gv[q].w};                       \
      xpose4(x, lane);                                                         \
      int nb = 16*q + 4*wid;                                                   \
      s16x4 vh, vl; split4(x, vh, vl);                                         \
      int B = (dV << 7) + (nb << 1);                                           \
      B ^= (dV & 7) << 4;                                                      \
      *(s16x4*)((char*)VtH + B) = vh;                                          \
      *(s16x4*)((char*)VtL + B) = vl;                                          \
    }                                                                          \
  }

#define K3V_COMPUTE()                                                          \
  {                                                                            \
    /* GEMM1: Z^T strip = K(strip) @ qlm^T */                                  \
    f32x4 zacc[4];                                                             \
    _Pragma("unroll")                                                          \
    for (int t = 0; t < 4; ++t) zacc[t] = (f32x4){0.f, 0.f, 0.f, 0.f};        \
    _Pragma("unroll")                                                          \
    for (int ks = 0; ks < 2; ++ks) {                                           \
      bf16x8 kh_ = ldP(KEh, wid*16 + lr, 4*ks + lg);                           \
      bf16x8 kl_ = ldP(KEl, wid*16 + lr, 4*ks + lg);                           \
      _Pragma("unroll")                                                        \
      for (int lt = 0; lt < 4; ++lt) {                                         \
        zacc[lt] = __builtin_amdgcn_mfma_f32_16x16x32_bf16(kh_, qbh[lt][ks], zacc[lt], 0, 0, 0); \
        zacc[lt] = __builtin_amdgcn_mfma_f32_16x16x32_bf16(kh_, qbl[lt][ks], zacc[lt], 0, 0, 0); \
        zacc[lt] = __builtin_amdgcn_mfma_f32_16x16x32_bf16(kl_, qbh[lt][ks], zacc[lt], 0, 0, 0); \
      }                                                                        \
    }                                                                          \
    /* exp, col-sum partials, pack E into register B-frags */                  \
    unsigned h01[4], h23[4], l01[4], l23[4];                                   \
    _Pragma("unroll")                                                          \
    for (int lt = 0; lt < 4; ++lt) {                                           \
      float e[4];                                                              \
      _Pragma("unroll")                                                        \
      for (int r = 0; r < 4; ++r) e[r] = __expf(zacc[lt][r]);                  \
      float s = e[0] + e[1] + e[2] + e[3];                                     \
      s += __shfl_xor(s, 16, 64);                                              \
      s += __shfl_xor(s, 32, 64);                                              \
      srw[lt] += s;                                                            \
      packsplit4(e, h01[lt], h23[lt], l01[lt], l23[lt]);                       \
    }                                                                          \
    /* GEMM2: acc2^T[d][l] += V^T(strip) @ E^T(strip); K=32 with upper half zeroed */ \
    const int src0 = (lr + ((2*lg) << 4)) & 63;                                \
    const int src1 = (lr + ((2*lg + 1) << 4)) & 63;                            \
    const bool act = (lg < 2);                                                 \
    bf16x8 Bh[4], Bl[4];                                                       \
    _Pragma("unroll")                                                          \
    for (int lt = 0; lt < 4; ++lt) {                                           \
      unsigned a0 = __shfl(h01[lt], src0, 64), a1 = __shfl(h23[lt], src0, 64); \
      unsigned a2 = __shfl(h01[lt], src1, 64), a3 = __shfl(h23[lt], src1, 64); \
      unsigned c0 = __shfl(l01[lt], src0, 64), c1 = __shfl(l23[lt], src0, 64); \
      unsigned c2 = __shfl(l01[lt], src1, 64), c3 = __shfl(l23[lt], src1, 64); \
      Bh[lt] = act ? mk8(a0, a1, a2, a3) : mk8(0, 0, 0, 0);                    \
      Bl[lt] = act ? mk8(c0, c1, c2, c3) : mk8(0, 0, 0, 0);                    \
    }                                                                          \
    _Pragma("unroll")                                                          \
    for (int dt = 0; dt < 4; ++dt) {                                           \
      bf16x8 vh = mk8(0,0,0,0), vl = mk8(0,0,0,0);                             \
      if (act) {                                                               \
        int d_ = dt*16 + lr;                                                   \
        int off = (d_ << 7) + ((wid*16 + lg*8) << 1);                          \
        off ^= (d_ & 7) << 4;                                                  \
        vh = *(const bf16x8*)((const char*)VtH + off);                         \
        vl = *(const bf16x8*)((const char*)VtL + off);                         \
      }                                                                        \
      _Pragma("unroll")                                                        \
      for (int lt = 0; lt < 4; ++lt) {                                         \
        acc2[dt][lt] = __builtin_amdgcn_mfma_f32_16x16x32_bf16(vh, Bh[lt], acc2[dt][lt], 0, 0, 0); \
        acc2[dt][lt] = __builtin_amdgcn_mfma_f32_16x16x32_bf16(vh, Bl[lt], acc2[dt][lt], 0, 0, 0); \
        acc2[dt][lt] = __builtin_amdgcn_mfma_f32_16x16x32_bf16(vl, Bh[lt], acc2[dt][lt], 0, 0, 0); \
      }                                                                        \
    }                                                                          \
  }

  K3V_LOAD(0)
  K3V_WRITE()
  __syncthreads();
  K3V_LOAD(1)
  K3V_COMPUTE()
  __syncthreads();
  K3V_WRITE()
  __syncthreads();
  K3V_COMPUTE()

  // ---- cross-wave reduce of acc2 through LDS (planes are dead now) ----
  __syncthreads();
  float4* slotA = (float4*)SM;              // 16 KB = 1024 float4
  float4* slotB = (float4*)(SM + 16384);
  if (wid == 1 || wid == 3) {
    float4* s = (wid == 1) ? slotA : slotB;
#pragma unroll
    for (int dt = 0; dt < 4; ++dt)
#pragma unroll
      for (int lt = 0; lt < 4; ++lt)
        s[(dt*4 + lt)*64 + lane] = make_float4(acc2[dt][lt][0], acc2[dt][lt][1], acc2[dt][lt][2], acc2[dt][lt][3]);
  }
  __syncthreads();
  if (wid == 0 || wid == 2) {
    float4* s = (wid == 0) ? slotA : slotB;
#pragma unroll
    for (int dt = 0; dt < 4; ++dt)
#pragma unroll
      for (int lt = 0; lt < 4; ++lt) {
        float4 v = s[(dt*4 + lt)*64 + lane];
        acc2[dt][lt][0] += v.x; acc2[dt][lt][1] += v.y; acc2[dt][lt][2] += v.z; acc2[dt][lt][3] += v.w;
      }
  }
  __syncthreads();
  if (wid == 2) {
#pragma unroll
    for (int dt = 0; dt < 4; ++dt)
#pragma unroll
      for (int lt = 0; lt < 4; ++lt)
        slotA[(dt*4 + lt)*64 + lane] = make_float4(acc2[dt][lt][0], acc2[dt][lt][1], acc2[dt][lt][2], acc2[dt][lt][3]);
  }
  __syncthreads();
  float* accp = ACC3p + ((size_t)tile*BHN + bh)*APROW;
  if (wid == 0) {
#pragma unroll
    for (int dt = 0; dt < 4; ++dt)
#pragma unroll
      for (int lt = 0; lt < 4; ++lt) {
        float4 v = slotA[(dt*4 + lt)*64 + lane];
        acc2[dt][lt][0] += v.x; acc2[dt][lt][1] += v.y; acc2[dt][lt][2] += v.z; acc2[dt][lt][3] += v.w;
        // store: row l = lt*16+lr, cols d = dt*16 + lg*4 .. +3
        *(float4*)&accp[(lt*16 + lr)*64 + dt*16 + lg*4] =
            make_float4(acc2[dt][lt][0], acc2[dt][lt][1], acc2[dt][lt][2], acc2[dt][lt][3]);
      }
  }
  // per-wave srow partials (col l = lt*16+lr); reduce_kernel sums the 4 waves
  if (lg == 0) {
#pragma unroll
    for (int lt = 0; lt < 4; ++lt)
      accp[4096 + wid*64 + lt*16 + lr] = srw[lt];
  }
}

// ---------------- Kernel B2: reduce partials -> ACC3, S3 ----------------
__global__ __launch_bounds__(256) void reduce_kernel(
    const float* __restrict__ ACC3p, float* __restrict__ ACC3, float* __restrict__ S3) {
  const int bh = blockIdx.y;
  const int f4 = blockIdx.x*256 + threadIdx.x;
  if (f4 < 1024) {
    float4 s = make_float4(0.f, 0.f, 0.f, 0.f);
    const float* base = ACC3p + (size_t)bh*APROW + f4*4;
#pragma unroll 4
    for (int t = 0; t < NTILE; ++t) {
      float4 v = *(const float4*)(base + (size_t)t*BHN*APROW);
      s.x += v.x; s.y += v.y; s.z += v.z; s.w += v.w;
    }
    *(float4*)&ACC3[(size_t)bh*4096 + f4*4] = s;
  } else if (f4 < 1040) {
    const int l0 = (f4 - 1024)*4;
    float4 s = make_float4(0.f, 0.f, 0.f, 0.f);
    const float* base = ACC3p + (size_t)bh*APROW + 4096 + l0;
    for (int t = 0; t < NTILE; ++t) {
      const float* tb = base + (size_t)t*BHN*APROW;
#pragma unroll
      for (int w = 0; w < 4; ++w) {
        float4 v = *(const float4*)(tb + w*64);
        s.x += v.x; s.y += v.y; s.z += v.z; s.w += v.w;
      }
    }
    *(float4*)&S3[bh*64 + l0] = s;
  }
}

// ---------------- Kernel C: kernel_2 softmax + Newton-Schulz (16 waves) ----------------
template<bool FUSE, bool HR, bool HC, bool HG>
__device__ __forceinline__ void mm_mfma(
    const float* __restrict__ Arow, const float* __restrict__ Scol,
    float diagc, float scale,
    float* __restrict__ OutRow, float* __restrict__ OutCol, float* __restrict__ OutGlob,
    int wr, int tn, int lane) {
  const int lr = lane & 15, lg = lane >> 4;
  f32x4 acc = (f32x4){0.f, 0.f, 0.f, 0.f};

#pragma unroll
  for (int ks = 0; ks < 2; ++ks) {
    const int kb = ks*32 + lg*8;
    float fa[8];
    const float* ap = Arow + (wr*16 + lr)*MATP + kb;
    *(float4*)&fa[0] = *(const float4*)ap;
    *(float4*)&fa[4] = *(const float4*)(ap + 4);
    bf16x8 ah, al; split8(fa, ah, al);
    float fb[8];
    const float* bp = Scol + (tn*16 + lr)*MATP + kb;
    *(float4*)&fb[0] = *(const float4*)bp;
    *(float4*)&fb[4] = *(const float4*)(bp + 4);
    if (FUSE) {
      int diff = (tn*16 + lr) - kb;
#pragma unroll
      for (int i = 0; i < 8; ++i) fb[i] = (i == diff ? diagc : 0.f) - fb[i];
    }
    bf16x8 bh_, bl_; split8(fb, bh_, bl_);
    acc = __builtin_amdgcn_mfma_f32_16x16x32_bf16(ah, bh_, acc, 0, 0, 0);
    acc = __builtin_amdgcn_mfma_f32_16x16x32_bf16(ah, bl_, acc, 0, 0, 0);
    acc = __builtin_amdgcn_mfma_f32_16x16x32_bf16(al, bh_, acc, 0, 0, 0);
  }
  __syncthreads();
  const int n = tn*16 + lr, m0 = wr*16 + lg*4;
  float v0 = scale*acc[0], v1 = scale*acc[1], v2 = scale*acc[2], v3 = scale*acc[3];
  if (HC) *(float4*)&OutCol[n*MATP + m0] = make_float4(v0, v1, v2, v3);
  if (HR) {
    OutRow[(m0+0)*MATP + n] = v0;
    OutRow[(m0+1)*MATP + n] = v1;
    OutRow[(m0+2)*MATP + n] = v2;
    OutRow[(m0+3)*MATP + n] = v3;
  }
  if (HG) {
    OutGlob[(m0+0)*64 + n] = v0;
    OutGlob[(m0+1)*64 + n] = v1;
    OutGlob[(m0+2)*64 + n] = v2;
    OutGlob[(m0+3)*64 + n] = v3;
  }
  __syncthreads();
}

__global__ __launch_bounds__(1024, 1) void inv_kernel(
    const float* __restrict__ qlm, const float* __restrict__ klm,
    const float* __restrict__ S3, const float* __restrict__ ACC3,
    float* __restrict__ W) {
  extern __shared__ float sm[];
  float* K2row = sm;
  float* Vmrow = sm + 1*MATE;
  float* Vmcol = sm + 2*MATE;
  float* Xrow  = sm + 3*MATE;
  float* Xcol  = sm + 4*MATE;
  float* Ycol  = sm + 5*MATE;
  float* Zcol  = sm + 6*MATE;
  float* rs    = sm + 7*MATE;        // 64 x 4 partials
  float* rinv  = rs + 256;           // 64
  float* red   = rinv + 64;          // 1
  const int bh = blockIdx.x, tid = threadIdx.x;
  const int wid = tid >> 6, lane = tid & 63;
  const int wr = wid & 3, tn = wid >> 2;
  const int lr = lane & 15, lg = lane >> 4;
  const int m0 = wr*16 + lg*4, n = tn*16 + lr;

  {
    int f = tid, r = f >> 4, c4 = (f & 15) << 2;
    *(float4*)&Xrow[r*MATP + c4] = *(const float4*)&qlm[(size_t)bh*4096 + f*4];
    *(float4*)&Xcol[r*MATP + c4] = *(const float4*)&klm[(size_t)bh*4096 + f*4];
  }
  __syncthreads();

  {
    f32x4 zacc = (f32x4){0.f, 0.f, 0.f, 0.f};
#pragma unroll
    for (int ks = 0; ks < 2; ++ks) {
      const int kb = ks*32 + lg*8;
      float fa[8];
      const float* ap = Xrow + (wr*16 + lr)*MATP + kb;
      *(float4*)&fa[0] = *(const float4*)ap;
      *(float4*)&fa[4] = *(const float4*)(ap + 4);
      bf16x8 ah, al; split8(fa, ah, al);
      float fb[8];
      const float* bp = Xcol + (tn*16 + lr)*MATP + kb;
      *(float4*)&fb[0] = *(const float4*)bp;
      *(float4*)&fb[4] = *(const float4*)(bp + 4);
      bf16x8 bh_, bl_; split8(fb, bh_, bl_);
      zacc = __builtin_amdgcn_mfma_f32_16x16x32_bf16(ah, bh_, zacc, 0, 0, 0);
      zacc = __builtin_amdgcn_mfma_f32_16x16x32_bf16(ah, bl_, zacc, 0, 0, 0);
      zacc = __builtin_amdgcn_mfma_f32_16x16x32_bf16(al, bh_, zacc, 0, 0, 0);
    }
    float e[4];
#pragma unroll
    for (int r = 0; r < 4; ++r) e[r] = __expf(zacc[r]);
    float part[4];
#pragma unroll
    for (int r = 0; r < 4; ++r) part[r] = shfl_sum16(e[r]);
    if (lr == 0) {
#pragma unroll
      for (int r = 0; r < 4; ++r) rs[(m0 + r)*4 + tn] = part[r];
    }
    __syncthreads();
    if (tid < 64)
      rinv[tid] = 1.0f / (rs[tid*4] + rs[tid*4+1] + rs[tid*4+2] + rs[tid*4+3]);
    __syncthreads();
#pragma unroll
    for (int r = 0; r < 4; ++r)
      K2row[(m0+r)*MATP + n] = e[r] * rinv[m0 + r];
  }
  __syncthreads();

  if (tid < 64) {
    float c = 0.f;
#pragma unroll 8
    for (int i = 0; i < 64; ++i) c += K2row[i*MATP + tid];
#pragma unroll
    for (int m = 1; m < 64; m <<= 1) c = fmaxf(c, __shfl_xor(c, m, 64));
    if (tid == 0) red[0] = 1.0f / c;
  }
  __syncthreads();
  const float invden = red[0];

  {
    int f = tid, i = f >> 4, c4 = (f & 15) << 2;
    float4 kv = *(const float4*)&K2row[i*MATP + c4];
    kv.x *= invden; kv.y *= invden; kv.z *= invden; kv.w *= invden;
    *(float4*)&Vmcol[i*MATP + c4] = kv;
    Vmrow[(c4+0)*MATP + i] = kv.x;
    Vmrow[(c4+1)*MATP + i] = kv.y;
    Vmrow[(c4+2)*MATP + i] = kv.z;
    Vmrow[(c4+3)*MATP + i] = kv.w;
  }
  __syncthreads();

  for (int it = 0; it < 6; ++it) {
    mm_mfma<false, true,  true,  false>(K2row, Vmcol, 0.f,  1.0f,  Xrow, Xcol, nullptr, wr, tn, lane);
    mm_mfma<true,  false, true,  false>(Xrow,  Xcol,  7.f,  1.0f,  nullptr, Ycol, nullptr, wr, tn, lane);
    mm_mfma<true,  false, true,  false>(Xrow,  Ycol,  15.f, 1.0f,  nullptr, Zcol, nullptr, wr, tn, lane);
    mm_mfma<true,  true,  true,  false>(Vmrow, Zcol,  13.f, 0.25f, Vmrow, Vmcol, nullptr, wr, tn, lane);
  }

  {
    int f = tid, k = f >> 4, c4 = (f & 15) << 2;
    float4 tv = *(const float4*)&ACC3[(size_t)bh*4096 + f*4];
    float ri = 1.0f / S3[bh*64 + k];
    Ycol[(c4+0)*MATP + k] = tv.x * ri;
    Ycol[(c4+1)*MATP + k] = tv.y * ri;
    Ycol[(c4+2)*MATP + k] = tv.z * ri;
    Ycol[(c4+3)*MATP + k] = tv.w * ri;
  }
  __syncthreads();
  mm_mfma<false, false, false, true>(Vmrow, Ycol, 0.f, 1.0f, nullptr, nullptr, W + (size_t)bh*4096, wr, tn, lane);
}

// ---------------- Kernel D: out = softmax(q k_lm^T) @ W (klm JIT, 4/CU) ----------------
__global__ __launch_bounds__(256, 4) void out_kernel(
    const float* __restrict__ Q, const float* __restrict__ klm,
    const float* __restrict__ W, float* __restrict__ Out) {
  __shared__ alignas(16) short WtH[64*64], WtL[64*64];  // W^T planes (16 KB)
  __shared__ alignas(16) float Prow[64*MATP];           // P fp32 (17.4 KB)
  const int bh = blockIdx.y, b = bh >> 4, h = bh & 15;
  const int n0 = blockIdx.x * 64;
  const int tid = threadIdx.x;
  const int wid = tid >> 6, lane = tid & 63;
  const int lr = lane & 15, lg = lane >> 4;
  const int m0 = wid*16 + lg*4;

  const int dW = 4*lr + lg;
#pragma unroll
  for (int q = 0; q < 4; ++q) {
    int f = tid + 256*q;
    int r = f >> 4, c4 = (f & 15) << 2;
    float4 wv = *(const float4*)&W[(size_t)bh*4096 + r*64 + c4];
    float x[4] = {wv.x, wv.y, wv.z, wv.w};
    xpose4(x, lane);
    int nb = 16*q + 4*wid;
    s16x4 wh, wl; split4(x, wh, wl);
    int B = (dW << 7) + (nb << 1);
    B ^= (dW & 7) << 4;
    *(s16x4*)((char*)WtH + B) = wh;
    *(s16x4*)((char*)WtL + B) = wl;
  }

  bf16x8 qh[2], qlo[2];
#pragma unroll
  for (int ks = 0; ks < 2; ++ks) {
    const float* qp = Q + ((size_t)b*NN + n0 + wid*16 + lr)*CC + h*HD + ks*32 + lg*8;
    float qf[8];
    *(float4*)&qf[0] = *(const float4*)qp;
    *(float4*)&qf[4] = *(const float4*)(qp + 4);
#pragma unroll
    for (int i = 0; i < 8; ++i) qf[i] *= 0.125f;
    split8(qf, qh[ks], qlo[ks]);
  }

  f32x4 zacc[4];
#pragma unroll
  for (int t = 0; t < 4; ++t) zacc[t] = (f32x4){0.f, 0.f, 0.f, 0.f};
#pragma unroll
  for (int tn = 0; tn < 4; ++tn) {
    const float* kp = &klm[(size_t)bh*4096 + (tn*16 + lr)*64 + lg*8];
    float4 k00 = *(const float4*)kp;
    float4 k01 = *(const float4*)(kp + 4);
    float4 k10 = *(const float4*)(kp + 32);
    float4 k11 = *(const float4*)(kp + 36);
    float kf[8];
    *(float4*)&kf[0] = k00; *(float4*)&kf[4] = k01;
    bf16x8 b0h, b0l; split8(kf, b0h, b0l);
    *(float4*)&kf[0] = k10; *(float4*)&kf[4] = k11;
    bf16x8 b1h, b1l; split8(kf, b1h, b1l);
    zacc[tn] = __builtin_amdgcn_mfma_f32_16x16x32_bf16(qh[0], b0h, zacc[tn], 0, 0, 0);
    zacc[tn] = __builtin_amdgcn_mfma_f32_16x16x32_bf16(qh[0], b0l, zacc[tn], 0, 0, 0);
    zacc[tn] = __builtin_amdgcn_mfma_f32_16x16x32_bf16(qlo[0], b0h, zacc[tn], 0, 0, 0);
    zacc[tn] = __builtin_amdgcn_mfma_f32_16x16x32_bf16(qh[1], b1h, zacc[tn], 0, 0, 0);
    zacc[tn] = __builtin_amdgcn_mfma_f32_16x16x32_bf16(qh[1], b1l, zacc[tn], 0, 0, 0);
    zacc[tn] = __builtin_amdgcn_mfma_f32_16x16x32_bf16(qlo[1], b1h, zacc[tn], 0, 0, 0);
  }
  float e[4][4];
#pragma unroll
  for (int tn = 0; tn < 4; ++tn)
#pragma unroll
    for (int r = 0; r < 4; ++r) e[tn][r] = __expf(zacc[tn][r]);
#pragma unroll
  for (int r = 0; r < 4; ++r) {
    float t = e[0][r] + e[1][r] + e[2][r] + e[3][r];
    t = shfl_sum16(t);
    float ri = 1.0f / t;
#pragma unroll
    for (int tn = 0; tn < 4; ++tn) e[tn][r] *= ri;
  }
#pragma unroll
  for (int tn = 0; tn < 4; ++tn) {
    const int n = tn*16 + lr;
#pragma unroll
    for (int r = 0; r < 4; ++r) Prow[(m0+r)*MATP + n] = e[tn][r];
  }
  __syncthreads();   // Wt visible

  f32x4 oacc[4];
#pragma unroll
  for (int t = 0; t < 4; ++t) oacc[t] = (f32x4){0.f, 0.f, 0.f, 0.f};
#pragma unroll
  for (int ks = 0; ks < 2; ++ks) {
    float fa[8];
    const float* ap = Prow + (wid*16 + lr)*MATP + ks*32 + lg*8;
    *(float4*)&fa[0] = *(const float4*)ap;
    *(float4*)&fa[4] = *(const float4*)(ap + 4);
    bf16x8 ah, al; split8(fa, ah, al);
#pragma unroll
    for (int tn = 0; tn < 4; ++tn) {
      bf16x8 bh_ = ldP(WtH, tn*16 + lr, 4*ks + lg);
      bf16x8 bl_ = ldP(WtL, tn*16 + lr, 4*ks + lg);
      oacc[tn] = __builtin_amdgcn_mfma_f32_16x16x32_bf16(ah, bh_, oacc[tn], 0, 0, 0);
      oacc[tn] = __builtin_amdgcn_mfma_f32_16x16x32_bf16(ah, bl_, oacc[tn], 0, 0, 0);
      oacc[tn] = __builtin_amdgcn_mfma_f32_16x16x32_bf16(al, bh_, oacc[tn], 0, 0, 0);
    }
  }
#pragma unroll
  for (int tn = 0; tn < 4; ++tn) {
    const int d = tn*16 + lr;
#pragma unroll
    for (int r = 0; r < 4; ++r)
      Out[((size_t)b*NN + n0 + m0 + r)*CC + h*HD + d] = oacc[tn][r];
  }
}

// ---------------- host ----------------
extern "C" void kernel_launch(void* const* d_in, const int* in_sizes, int n_in,
                              void* d_out, int out_size, void* d_ws, size_t ws_size,
                              hipStream_t stream) {
  const float* Q = (const float*)d_in[0];
  const float* K = (const float*)d_in[1];
  const float* V = (const float*)d_in[2];
  float* out = (float*)d_out;
  float* ws  = (float*)d_ws;

  float* qlm   = ws;                // 262144 floats
  float* klm   = ws + 262144;       // 262144
  float* S3    = ws + 524288;       // 4096
  float* ACC3  = ws + 528384;       // 262144
  float* Wm    = ws + 790528;       // 262144
  float* ACC3p = ws + 1052672;      // 32*64*4352 = 8,912,896 floats (~36 MB)

  size_t shC = (size_t)(7*MATE + 384)*sizeof(float);   // ~123 KB
  hipFuncSetAttribute((const void*)inv_kernel,
                      hipFuncAttributeMaxDynamicSharedMemorySize, (int)shC);

  lm_kernel    <<<dim3(16, BHN), 256, 0, stream>>>(Q, K, qlm, klm);
  k3v_kernel   <<<dim3(NTILE, BHN), 256, 0, stream>>>(K, V, qlm, ACC3p);
  reduce_kernel<<<dim3(5, BHN), 256, 0, stream>>>(ACC3p, ACC3, S3);
  inv_kernel   <<<dim3(BHN),    1024, shC, stream>>>(qlm, klm, S3, ACC3, Wm);
  out_kernel   <<<dim3(64, BHN), 256, 0, stream>>>(Q, klm, Wm, out);
}

// Round 11
// 154.238 us; speedup vs baseline: 1.2447x; 1.2447x over previous
//
#include <hip/hip_runtime.h>
#include <math.h>

#define BB 4
#define NN 4096
#define CC 1024
#define HH 16
#define HD 64
#define LM 64
#define SEG 64
#define BHN (BB*HH)          // 64
#define MATP 68              // fp32 row stride (inv buffers + Prow)
#define MATE (64*MATP)
#define NTILE 32             // k3v grid.x

typedef __attribute__((ext_vector_type(8))) short bf16x8;
typedef __attribute__((ext_vector_type(4))) short s16x4;
typedef __attribute__((ext_vector_type(4))) float f32x4;

__device__ __forceinline__ float shfl_sum16(float v) {
  v += __shfl_xor(v, 1, 16);
  v += __shfl_xor(v, 2, 16);
  v += __shfl_xor(v, 4, 16);
  v += __shfl_xor(v, 8, 16);
  return v;
}

// split fp32 -> bf16 hi (chop) + bf16 lo (chop of residual); rel err ~2^-16
__device__ __forceinline__ void split8(const float* f, bf16x8& hi, bf16x8& lo) {
#pragma unroll
  for (int i = 0; i < 8; ++i) {
    unsigned u = __builtin_bit_cast(unsigned, f[i]);
    float hf = __builtin_bit_cast(float, u & 0xFFFF0000u);
    hi[i] = (short)(u >> 16);
    float l = f[i] - hf;
    unsigned ul = __builtin_bit_cast(unsigned, l);
    lo[i] = (short)(ul >> 16);
  }
}

__device__ __forceinline__ void split4(const float* f, s16x4& hi, s16x4& lo) {
#pragma unroll
  for (int i = 0; i < 4; ++i) {
    unsigned u = __builtin_bit_cast(unsigned, f[i]);
    float hf = __builtin_bit_cast(float, u & 0xFFFF0000u);
    hi[i] = (short)(u >> 16);
    float l = f[i] - hf;
    unsigned ul = __builtin_bit_cast(unsigned, l);
    lo[i] = (short)(ul >> 16);
  }
}

// m214-style plane: 64 rows x 64 shorts (128B rows), byte ^= (row&7)<<4.
__device__ __forceinline__ int planeAddr(int row, int cd) {
  int B = (row << 7) + (cd << 4);
  return B ^ ((row & 7) << 4);
}
__device__ __forceinline__ bf16x8 ldP(const short* __restrict__ P, int row, int cd) {
  return *(const bf16x8*)((const char*)P + planeAddr(row, cd));
}

// in-wave 4x4 transpose among lanes {l, l^16, l^32, l^48}
__device__ __forceinline__ void xpose4(float x[4], int lane) {
  bool p1 = (lane >> 4) & 1;
  float s0 = p1 ? x[0] : x[1], s1 = p1 ? x[2] : x[3];
  float r0 = __shfl_xor(s0, 16, 64), r1 = __shfl_xor(s1, 16, 64);
  if (p1) { x[0] = r0; x[2] = r1; } else { x[1] = r0; x[3] = r1; }
  bool p2 = (lane >> 5) & 1;
  s0 = p2 ? x[0] : x[2]; s1 = p2 ? x[1] : x[3];
  r0 = __shfl_xor(s0, 32, 64); r1 = __shfl_xor(s1, 32, 64);
  if (p2) { x[0] = r0; x[1] = r1; } else { x[2] = r0; x[3] = r1; }
}

// ---------------- Kernel A: Q landmark means (K pooling folded into k3v) ----------------
__global__ __launch_bounds__(256) void lm_q_kernel(
    const float* __restrict__ Q, float* __restrict__ qlm) {
  int bh = blockIdx.y; int b = bh >> 4; int h = bh & 15;
  int tid = threadIdx.x;
  int l = blockIdx.x * 4 + (tid >> 6);
  int d = tid & 63;
  const float* qbase = Q + ((size_t)b*NN + (size_t)l*SEG)*CC + h*HD + d;
  float sq = 0.f;
#pragma unroll 8
  for (int s = 0; s < SEG; ++s) sq += qbase[(size_t)s*CC];
  qlm[(size_t)bh*4096 + l*64 + d] = sq * (1.0f/(64.0f*8.0f));  // mean then /sqrt(hd)
}

// ---------------- Kernel B: kernel_3 partials + klm pooling (E aliased on K planes) ----------------
__global__ __launch_bounds__(256, 4) void k3v_kernel(
    const float* __restrict__ K, const float* __restrict__ V,
    const float* __restrict__ qlm, float* __restrict__ klm,
    float* __restrict__ S3, float* __restrict__ ACC3) {
  __shared__ alignas(16) char PlaneA[16384];   // K bf16 planes, then E fp32 (aliased)
  __shared__ alignas(16) char PlaneB[16384];   // V^T bf16 planes
  __shared__ alignas(16) float kred[256];      // per-wave klm partials
  short* KEh = (short*)PlaneA;
  short* KEl = (short*)(PlaneA + 8192);
  short* VtH = (short*)PlaneB;
  short* VtL = (short*)(PlaneB + 8192);
  const int bh = blockIdx.y, b = bh >> 4, h = bh & 15;
  const int tile = blockIdx.x, tid = threadIdx.x;
  const int wid = tid >> 6, lane = tid & 63;
  const int lr = lane & 15, lg = lane >> 4;
  const int m0 = wid*16 + lg*4;
  const int dV = 4*lr + lg;

  // qlm A-fragments -> registers (split once)
  bf16x8 qh[2], ql[2];
#pragma unroll
  for (int ks = 0; ks < 2; ++ks) {
    const float* qp = qlm + (size_t)bh*4096 + (wid*16 + lr)*64 + ks*32 + lg*8;
    float qf[8];
    *(float4*)&qf[0] = *(const float4*)qp;
    *(float4*)&qf[4] = *(const float4*)(qp + 4);
    split8(qf, qh[ks], ql[ks]);
  }

  f32x4 acc2[4];
#pragma unroll
  for (int t = 0; t < 4; ++t) acc2[t] = (f32x4){0.f, 0.f, 0.f, 0.f};
  float srow[4] = {0.f, 0.f, 0.f, 0.f};
  float ee[4][4];

  const int rk0 = tid >> 3, ck = tid & 7;
  const int rk1 = (tid + 256) >> 3;
  float4 gk[2][2], gv[4];

#define K3V_LOAD(SUB)                                                          \
  {                                                                            \
    const int n0_ = tile*128 + (SUB)*64;                                       \
    const float* kb0 = &K[((size_t)b*NN + n0_ + rk0)*CC + h*HD + ck*8];        \
    const float* kb1 = &K[((size_t)b*NN + n0_ + rk1)*CC + h*HD + ck*8];        \
    gk[0][0] = *(const float4*)kb0;  gk[0][1] = *(const float4*)(kb0 + 4);     \
    gk[1][0] = *(const float4*)kb1;  gk[1][1] = *(const float4*)(kb1 + 4);     \
    _Pragma("unroll")                                                          \
    for (int q = 0; q < 4; ++q) {                                              \
      int f = tid + 256*q;                                                     \
      int r = f >> 4, c4 = (f & 15) << 2;                                      \
      gv[q] = *(const float4*)&V[((size_t)b*NN + n0_ + r)*CC + h*HD + c4];     \
    }                                                                          \
  }

// stage K planes + V^T planes, and compute klm partials from fp32 gk
#define K3V_WRITE()                                                            \
  {                                                                            \
    _Pragma("unroll")                                                          \
    for (int q2 = 0; q2 < 2; ++q2) {                                           \
      float kf[8];                                                             \
      *(float4*)&kf[0] = gk[q2][0];                                            \
      *(float4*)&kf[4] = gk[q2][1];                                            \
      bf16x8 khv, klv; split8(kf, khv, klv);                                   \
      int r = q2 ? rk1 : rk0;                                                  \
      int A = planeAddr(r, ck);                                                \
      *(bf16x8*)((char*)KEh + A) = khv;                                        \
      *(bf16x8*)((char*)KEl + A) = klv;                                        \
    }                                                                          \
    /* klm partial: sum my 2 rows, reduce over 8 lanes sharing ck */           \
    {                                                                          \
      float s8[8];                                                             \
      s8[0] = gk[0][0].x + gk[1][0].x;  s8[1] = gk[0][0].y + gk[1][0].y;       \
      s8[2] = gk[0][0].z + gk[1][0].z;  s8[3] = gk[0][0].w + gk[1][0].w;       \
      s8[4] = gk[0][1].x + gk[1][1].x;  s8[5] = gk[0][1].y + gk[1][1].y;       \
      s8[6] = gk[0][1].z + gk[1][1].z;  s8[7] = gk[0][1].w + gk[1][1].w;       \
      _Pragma("unroll")                                                        \
      for (int m = 8; m < 64; m <<= 1) {                                       \
        _Pragma("unroll")                                                      \
        for (int i = 0; i < 8; ++i) s8[i] += __shfl_xor(s8[i], m, 64);         \
      }                                                                        \
      if (lane < 8) {                                                          \
        *(float4*)&kred[wid*64 + lane*8]     = make_float4(s8[0], s8[1], s8[2], s8[3]); \
        *(float4*)&kred[wid*64 + lane*8 + 4] = make_float4(s8[4], s8[5], s8[6], s8[7]); \
      }                                                                        \
    }                                                                          \
    _Pragma("unroll")                                                          \
    for (int q = 0; q < 4; ++q) {                                              \
      float x[4] = {gv[q].x, gv[q].y, gv[q].z, gv[q].w};                       \
      xpose4(x, lane);                                                         \
      int nb = 16*q + 4*wid;                                                   \
      s16x4 vh, vl; split4(x, vh, vl);                                         \
      int B = (dV << 7) + (nb << 1);                                           \
      B ^= (dV & 7) << 4;                                                      \
      *(s16x4*)((char*)VtH + B) = vh;                                          \
      *(s16x4*)((char*)VtL + B) = vl;                                          \
    }                                                                          \
  }

// finalize klm row for segment (tile*2+SUB); kred written pre-barrier
#define K3V_KFIN(SUB)                                                          \
  if (tid < 64) {                                                              \
    klm[(size_t)bh*4096 + (tile*2 + (SUB))*64 + tid] =                         \
        (kred[tid] + kred[64+tid] + kred[128+tid] + kred[192+tid]) * (1.0f/64.0f); \
  }

// GEMM1: z[l][n] over d (reads K planes, all rows) -> ee + srow
#define K3V_GEMM1()                                                            \
  {                                                                            \
    f32x4 zacc[4];                                                             \
    _Pragma("unroll")                                                          \
    for (int t = 0; t < 4; ++t) zacc[t] = (f32x4){0.f, 0.f, 0.f, 0.f};        \
    _Pragma("unroll")                                                          \
    for (int ks = 0; ks < 2; ++ks) {                                           \
      _Pragma("unroll")                                                        \
      for (int tn = 0; tn < 4; ++tn) {                                         \
        bf16x8 bh_ = ldP(KEh, tn*16 + lr, 4*ks + lg);                          \
        bf16x8 bl_ = ldP(KEl, tn*16 + lr, 4*ks + lg);                          \
        zacc[tn] = __builtin_amdgcn_mfma_f32_16x16x32_bf16(qh[ks], bh_, zacc[tn], 0, 0, 0); \
        zacc[tn] = __builtin_amdgcn_mfma_f32_16x16x32_bf16(qh[ks], bl_, zacc[tn], 0, 0, 0); \
        zacc[tn] = __builtin_amdgcn_mfma_f32_16x16x32_bf16(ql[ks], bh_, zacc[tn], 0, 0, 0); \
      }                                                                        \
    }                                                                          \
    _Pragma("unroll")                                                          \
    for (int tn = 0; tn < 4; ++tn)                                             \
      _Pragma("unroll")                                                        \
      for (int r = 0; r < 4; ++r) ee[tn][r] = __expf(zacc[tn][r]);             \
    _Pragma("unroll")                                                          \
    for (int r = 0; r < 4; ++r) {                                              \
      float t = ee[0][r] + ee[1][r] + ee[2][r] + ee[3][r];                     \
      srow[r] += shfl_sum16(t);                                                \
    }                                                                          \
  }

// E-store (fp32, stride 64, XOR swizzle) into PlaneA (K planes dead) + GEMM2
#define K3V_EG2()                                                              \
  {                                                                            \
    _Pragma("unroll")                                                          \
    for (int tn = 0; tn < 4; ++tn) {                                           \
      _Pragma("unroll")                                                        \
      for (int r = 0; r < 4; ++r) {                                            \
        int row = m0 + r;                                                      \
        int byte = row*256 + (tn*16 + lr)*4;                                   \
        byte ^= (row & 7) << 4;                                                \
        *(float*)(PlaneA + byte) = ee[tn][r];                                  \
      }                                                                        \
    }                                                                          \
    _Pragma("unroll")                                                          \
    for (int ks = 0; ks < 2; ++ks) {                                           \
      int row = wid*16 + lr;                                                   \
      int swz = (row & 7) << 4;                                                \
      int base = row*256 + ks*128 + lg*32;                                     \
      float fa[8];                                                             \
      *(float4*)&fa[0] = *(const float4*)(PlaneA + (base ^ swz));              \
      *(float4*)&fa[4] = *(const float4*)(PlaneA + ((base + 16) ^ swz));       \
      bf16x8 ah, al; split8(fa, ah, al);                                       \
      _Pragma("unroll")                                                        \
      for (int tn = 0; tn < 4; ++tn) {                                         \
        bf16x8 bh_ = ldP(VtH, tn*16 + lr, 4*ks + lg);                          \
        bf16x8 bl_ = ldP(VtL, tn*16 + lr, 4*ks + lg);                          \
        acc2[tn] = __builtin_amdgcn_mfma_f32_16x16x32_bf16(ah, bh_, acc2[tn], 0, 0, 0); \
        acc2[tn] = __builtin_amdgcn_mfma_f32_16x16x32_bf16(ah, bl_, acc2[tn], 0, 0, 0); \
        acc2[tn] = __builtin_amdgcn_mfma_f32_16x16x32_bf16(al, bh_, acc2[tn], 0, 0, 0); \
      }                                                                        \
    }                                                                          \
  }

  K3V_LOAD(0)
  K3V_WRITE()
  __syncthreads();      // planes + kred visible
  K3V_LOAD(1)           // prefetch sub 1 under compute
  K3V_GEMM1()
  K3V_KFIN(0)
  __syncthreads();      // K-plane reads done -> E may overwrite
  K3V_EG2()
  __syncthreads();      // E + Vt reads done -> restage
  K3V_WRITE()
  __syncthreads();
  K3V_GEMM1()
  K3V_KFIN(1)
  __syncthreads();
  K3V_EG2()

  if (lr == 0) {
#pragma unroll
    for (int r = 0; r < 4; ++r)
      atomicAdd(&S3[bh*64 + m0 + r], srow[r]);
  }
#pragma unroll
  for (int tn = 0; tn < 4; ++tn)
#pragma unroll
    for (int r = 0; r < 4; ++r)
      atomicAdd(&ACC3[(size_t)bh*4096 + (m0 + r)*64 + tn*16 + lr], acc2[tn][r]);
}

// ---------------- Kernel C: kernel_2 softmax + Newton-Schulz (16 waves) ----------------
template<bool FUSE, bool HR, bool HC, bool HG>
__device__ __forceinline__ void mm_mfma(
    const float* __restrict__ Arow, const float* __restrict__ Scol,
    float diagc, float scale,
    float* __restrict__ OutRow, float* __restrict__ OutCol, float* __restrict__ OutGlob,
    int wr, int tn, int lane) {
  const int lr = lane & 15, lg = lane >> 4;
  f32x4 acc = (f32x4){0.f, 0.f, 0.f, 0.f};

#pragma unroll
  for (int ks = 0; ks < 2; ++ks) {
    const int kb = ks*32 + lg*8;
    float fa[8];
    const float* ap = Arow + (wr*16 + lr)*MATP + kb;
    *(float4*)&fa[0] = *(const float4*)ap;
    *(float4*)&fa[4] = *(const float4*)(ap + 4);
    bf16x8 ah, al; split8(fa, ah, al);
    float fb[8];
    const float* bp = Scol + (tn*16 + lr)*MATP + kb;
    *(float4*)&fb[0] = *(const float4*)bp;
    *(float4*)&fb[4] = *(const float4*)(bp + 4);
    if (FUSE) {
      int diff = (tn*16 + lr) - kb;
#pragma unroll
      for (int i = 0; i < 8; ++i) fb[i] = (i == diff ? diagc : 0.f) - fb[i];
    }
    bf16x8 bh_, bl_; split8(fb, bh_, bl_);
    acc = __builtin_amdgcn_mfma_f32_16x16x32_bf16(ah, bh_, acc, 0, 0, 0);
    acc = __builtin_amdgcn_mfma_f32_16x16x32_bf16(ah, bl_, acc, 0, 0, 0);
    acc = __builtin_amdgcn_mfma_f32_16x16x32_bf16(al, bh_, acc, 0, 0, 0);
  }
  __syncthreads();
  const int n = tn*16 + lr, m0 = wr*16 + lg*4;
  float v0 = scale*acc[0], v1 = scale*acc[1], v2 = scale*acc[2], v3 = scale*acc[3];
  if (HC) *(float4*)&OutCol[n*MATP + m0] = make_float4(v0, v1, v2, v3);
  if (HR) {
    OutRow[(m0+0)*MATP + n] = v0;
    OutRow[(m0+1)*MATP + n] = v1;
    OutRow[(m0+2)*MATP + n] = v2;
    OutRow[(m0+3)*MATP + n] = v3;
  }
  if (HG) {
    OutGlob[(m0+0)*64 + n] = v0;
    OutGlob[(m0+1)*64 + n] = v1;
    OutGlob[(m0+2)*64 + n] = v2;
    OutGlob[(m0+3)*64 + n] = v3;
  }
  __syncthreads();
}

__global__ __launch_bounds__(1024, 1) void inv_kernel(
    const float* __restrict__ qlm, const float* __restrict__ klm,
    const float* __restrict__ S3, const float* __restrict__ ACC3,
    float* __restrict__ W) {
  extern __shared__ float sm[];
  float* K2row = sm;
  float* Vmrow = sm + 1*MATE;
  float* Vmcol = sm + 2*MATE;
  float* Xrow  = sm + 3*MATE;
  float* Xcol  = sm + 4*MATE;
  float* Ycol  = sm + 5*MATE;
  float* Zcol  = sm + 6*MATE;
  float* rs    = sm + 7*MATE;        // 64 x 4 partials
  float* rinv  = rs + 256;           // 64
  float* red   = rinv + 64;          // 1
  const int bh = blockIdx.x, tid = threadIdx.x;
  const int wid = tid >> 6, lane = tid & 63;
  const int wr = wid & 3, tn = wid >> 2;
  const int lr = lane & 15, lg = lane >> 4;
  const int m0 = wr*16 + lg*4, n = tn*16 + lr;

  {
    int f = tid, r = f >> 4, c4 = (f & 15) << 2;
    *(float4*)&Xrow[r*MATP + c4] = *(const float4*)&qlm[(size_t)bh*4096 + f*4];
    *(float4*)&Xcol[r*MATP + c4] = *(const float4*)&klm[(size_t)bh*4096 + f*4];
  }
  __syncthreads();

  {
    f32x4 zacc = (f32x4){0.f, 0.f, 0.f, 0.f};
#pragma unroll
    for (int ks = 0; ks < 2; ++ks) {
      const int kb = ks*32 + lg*8;
      float fa[8];
      const float* ap = Xrow + (wr*16 + lr)*MATP + kb;
      *(float4*)&fa[0] = *(const float4*)ap;
      *(float4*)&fa[4] = *(const float4*)(ap + 4);
      bf16x8 ah, al; split8(fa, ah, al);
      float fb[8];
      const float* bp = Xcol + (tn*16 + lr)*MATP + kb;
      *(float4*)&fb[0] = *(const float4*)bp;
      *(float4*)&fb[4] = *(const float4*)(bp + 4);
      bf16x8 bh_, bl_; split8(fb, bh_, bl_);
      zacc = __builtin_amdgcn_mfma_f32_16x16x32_bf16(ah, bh_, zacc, 0, 0, 0);
      zacc = __builtin_amdgcn_mfma_f32_16x16x32_bf16(ah, bl_, zacc, 0, 0, 0);
      zacc = __builtin_amdgcn_mfma_f32_16x16x32_bf16(al, bh_, zacc, 0, 0, 0);
    }
    float e[4];
#pragma unroll
    for (int r = 0; r < 4; ++r) e[r] = __expf(zacc[r]);
    float part[4];
#pragma unroll
    for (int r = 0; r < 4; ++r) part[r] = shfl_sum16(e[r]);
    if (lr == 0) {
#pragma unroll
      for (int r = 0; r < 4; ++r) rs[(m0 + r)*4 + tn] = part[r];
    }
    __syncthreads();
    if (tid < 64)
      rinv[tid] = 1.0f / (rs[tid*4] + rs[tid*4+1] + rs[tid*4+2] + rs[tid*4+3]);
    __syncthreads();
#pragma unroll
    for (int r = 0; r < 4; ++r)
      K2row[(m0+r)*MATP + n] = e[r] * rinv[m0 + r];
  }
  __syncthreads();

  if (tid < 64) {
    float c = 0.f;
#pragma unroll 8
    for (int i = 0; i < 64; ++i) c += K2row[i*MATP + tid];
#pragma unroll
    for (int m = 1; m < 64; m <<= 1) c = fmaxf(c, __shfl_xor(c, m, 64));
    if (tid == 0) red[0] = 1.0f / c;
  }
  __syncthreads();
  const float invden = red[0];

  {
    int f = tid, i = f >> 4, c4 = (f & 15) << 2;
    float4 kv = *(const float4*)&K2row[i*MATP + c4];
    kv.x *= invden; kv.y *= invden; kv.z *= invden; kv.w *= invden;
    *(float4*)&Vmcol[i*MATP + c4] = kv;
    Vmrow[(c4+0)*MATP + i] = kv.x;
    Vmrow[(c4+1)*MATP + i] = kv.y;
    Vmrow[(c4+2)*MATP + i] = kv.z;
    Vmrow[(c4+3)*MATP + i] = kv.w;
  }
  __syncthreads();

  for (int it = 0; it < 6; ++it) {
    mm_mfma<false, true,  true,  false>(K2row, Vmcol, 0.f,  1.0f,  Xrow, Xcol, nullptr, wr, tn, lane);
    mm_mfma<true,  false, true,  false>(Xrow,  Xcol,  7.f,  1.0f,  nullptr, Ycol, nullptr, wr, tn, lane);
    mm_mfma<true,  false, true,  false>(Xrow,  Ycol,  15.f, 1.0f,  nullptr, Zcol, nullptr, wr, tn, lane);
    mm_mfma<true,  true,  true,  false>(Vmrow, Zcol,  13.f, 0.25f, Vmrow, Vmcol, nullptr, wr, tn, lane);
  }

  {
    int f = tid, k = f >> 4, c4 = (f & 15) << 2;
    float4 tv = *(const float4*)&ACC3[(size_t)bh*4096 + f*4];
    float ri = 1.0f / S3[bh*64 + k];
    Ycol[(c4+0)*MATP + k] = tv.x * ri;
    Ycol[(c4+1)*MATP + k] = tv.y * ri;
    Ycol[(c4+2)*MATP + k] = tv.z * ri;
    Ycol[(c4+3)*MATP + k] = tv.w * ri;
  }
  __syncthreads();
  mm_mfma<false, false, false, true>(Vmrow, Ycol, 0.f, 1.0f, nullptr, nullptr, W + (size_t)bh*4096, wr, tn, lane);
}

// ---------------- Kernel D: out = softmax(q k_lm^T) @ W (klm JIT, 4/CU) ----------------
__global__ __launch_bounds__(256, 4) void out_kernel(
    const float* __restrict__ Q, const float* __restrict__ klm,
    const float* __restrict__ W, float* __restrict__ Out) {
  __shared__ alignas(16) short WtH[64*64], WtL[64*64];  // W^T planes (16 KB)
  __shared__ alignas(16) float Prow[64*MATP];           // P fp32 (17.4 KB)
  const int bh = blockIdx.y, b = bh >> 4, h = bh & 15;
  const int n0 = blockIdx.x * 64;
  const int tid = threadIdx.x;
  const int wid = tid >> 6, lane = tid & 63;
  const int lr = lane & 15, lg = lane >> 4;
  const int m0 = wid*16 + lg*4;

  const int dW = 4*lr + lg;
#pragma unroll
  for (int q = 0; q < 4; ++q) {
    int f = tid + 256*q;
    int r = f >> 4, c4 = (f & 15) << 2;
    float4 wv = *(const float4*)&W[(size_t)bh*4096 + r*64 + c4];
    float x[4] = {wv.x, wv.y, wv.z, wv.w};
    xpose4(x, lane);
    int nb = 16*q + 4*wid;
    s16x4 wh, wl; split4(x, wh, wl);
    int B = (dW << 7) + (nb << 1);
    B ^= (dW & 7) << 4;
    *(s16x4*)((char*)WtH + B) = wh;
    *(s16x4*)((char*)WtL + B) = wl;
  }

  bf16x8 qh[2], qlo[2];
#pragma unroll
  for (int ks = 0; ks < 2; ++ks) {
    const float* qp = Q + ((size_t)b*NN + n0 + wid*16 + lr)*CC + h*HD + ks*32 + lg*8;
    float qf[8];
    *(float4*)&qf[0] = *(const float4*)qp;
    *(float4*)&qf[4] = *(const float4*)(qp + 4);
#pragma unroll
    for (int i = 0; i < 8; ++i) qf[i] *= 0.125f;
    split8(qf, qh[ks], qlo[ks]);
  }

  f32x4 zacc[4];
#pragma unroll
  for (int t = 0; t < 4; ++t) zacc[t] = (f32x4){0.f, 0.f, 0.f, 0.f};
#pragma unroll
  for (int tn = 0; tn < 4; ++tn) {
    const float* kp = &klm[(size_t)bh*4096 + (tn*16 + lr)*64 + lg*8];
    float4 k00 = *(const float4*)kp;
    float4 k01 = *(const float4*)(kp + 4);
    float4 k10 = *(const float4*)(kp + 32);
    float4 k11 = *(const float4*)(kp + 36);
    float kf[8];
    *(float4*)&kf[0] = k00; *(float4*)&kf[4] = k01;
    bf16x8 b0h, b0l; split8(kf, b0h, b0l);
    *(float4*)&kf[0] = k10; *(float4*)&kf[4] = k11;
    bf16x8 b1h, b1l; split8(kf, b1h, b1l);
    zacc[tn] = __builtin_amdgcn_mfma_f32_16x16x32_bf16(qh[0], b0h, zacc[tn], 0, 0, 0);
    zacc[tn] = __builtin_amdgcn_mfma_f32_16x16x32_bf16(qh[0], b0l, zacc[tn], 0, 0, 0);
    zacc[tn] = __builtin_amdgcn_mfma_f32_16x16x32_bf16(qlo[0], b0h, zacc[tn], 0, 0, 0);
    zacc[tn] = __builtin_amdgcn_mfma_f32_16x16x32_bf16(qh[1], b1h, zacc[tn], 0, 0, 0);
    zacc[tn] = __builtin_amdgcn_mfma_f32_16x16x32_bf16(qh[1], b1l, zacc[tn], 0, 0, 0);
    zacc[tn] = __builtin_amdgcn_mfma_f32_16x16x32_bf16(qlo[1], b1h, zacc[tn], 0, 0, 0);
  }
  float e[4][4];
#pragma unroll
  for (int tn = 0; tn < 4; ++tn)
#pragma unroll
    for (int r = 0; r < 4; ++r) e[tn][r] = __expf(zacc[tn][r]);
#pragma unroll
  for (int r = 0; r < 4; ++r) {
    float t = e[0][r] + e[1][r] + e[2][r] + e[3][r];
    t = shfl_sum16(t);
    float ri = 1.0f / t;
#pragma unroll
    for (int tn = 0; tn < 4; ++tn) e[tn][r] *= ri;
  }
#pragma unroll
  for (int tn = 0; tn < 4; ++tn) {
    const int n = tn*16 + lr;
#pragma unroll
    for (int r = 0; r < 4; ++r) Prow[(m0+r)*MATP + n] = e[tn][r];
  }
  __syncthreads();   // Wt visible

  f32x4 oacc[4];
#pragma unroll
  for (int t = 0; t < 4; ++t) oacc[t] = (f32x4){0.f, 0.f, 0.f, 0.f};
#pragma unroll
  for (int ks = 0; ks < 2; ++ks) {
    float fa[8];
    const float* ap = Prow + (wid*16 + lr)*MATP + ks*32 + lg*8;
    *(float4*)&fa[0] = *(const float4*)ap;
    *(float4*)&fa[4] = *(const float4*)(ap + 4);
    bf16x8 ah, al; split8(fa, ah, al);
#pragma unroll
    for (int tn = 0; tn < 4; ++tn) {
      bf16x8 bh_ = ldP(WtH, tn*16 + lr, 4*ks + lg);
      bf16x8 bl_ = ldP(WtL, tn*16 + lr, 4*ks + lg);
      oacc[tn] = __builtin_amdgcn_mfma_f32_16x16x32_bf16(ah, bh_, oacc[tn], 0, 0, 0);
      oacc[tn] = __builtin_amdgcn_mfma_f32_16x16x32_bf16(ah, bl_, oacc[tn], 0, 0, 0);
      oacc[tn] = __builtin_amdgcn_mfma_f32_16x16x32_bf16(al, bh_, oacc[tn], 0, 0, 0);
    }
  }
#pragma unroll
  for (int tn = 0; tn < 4; ++tn) {
    const int d = tn*16 + lr;
#pragma unroll
    for (int r = 0; r < 4; ++r)
      Out[((size_t)b*NN + n0 + m0 + r)*CC + h*HD + d] = oacc[tn][r];
  }
}

// ---------------- host ----------------
extern "C" void kernel_launch(void* const* d_in, const int* in_sizes, int n_in,
                              void* d_out, int out_size, void* d_ws, size_t ws_size,
                              hipStream_t stream) {
  const float* Q = (const float*)d_in[0];
  const float* K = (const float*)d_in[1];
  const float* V = (const float*)d_in[2];
  float* out = (float*)d_out;
  float* ws  = (float*)d_ws;

  float* qlm  = ws;               // 262144 floats
  float* klm  = ws + 262144;      // 262144
  float* S3   = ws + 524288;      // 4096
  float* ACC3 = ws + 528384;      // 262144
  float* Wm   = ws + 790528;      // 262144

  size_t shC = (size_t)(7*MATE + 384)*sizeof(float);   // ~123 KB
  hipFuncSetAttribute((const void*)inv_kernel,
                      hipFuncAttributeMaxDynamicSharedMemorySize, (int)shC);

  // zero S3 + ACC3 (contiguous) for atomic accumulation
  hipMemsetAsync(S3, 0, (4096 + 262144)*sizeof(float), stream);

  lm_q_kernel<<<dim3(16, BHN), 256, 0, stream>>>(Q, qlm);
  k3v_kernel <<<dim3(NTILE, BHN), 256, 0, stream>>>(K, V, qlm, klm, S3, ACC3);
  inv_kernel <<<dim3(BHN),    1024, shC, stream>>>(qlm, klm, S3, ACC3, Wm);
  out_kernel <<<dim3(64, BHN), 256, 0, stream>>>(Q, klm, Wm, out);
}

// Round 12
// 147.923 us; speedup vs baseline: 1.2978x; 1.0427x over previous
//
#include <hip/hip_runtime.h>
#include <math.h>

#define BB 4
#define NN 4096
#define CC 1024
#define HH 16
#define HD 64
#define LM 64
#define SEG 64
#define BHN (BB*HH)          // 64
#define MATP 68              // fp32 row stride (inv buffers + Prow)
#define MATE (64*MATP)

typedef __attribute__((ext_vector_type(8))) short bf16x8;
typedef __attribute__((ext_vector_type(4))) short s16x4;
typedef __attribute__((ext_vector_type(4))) float f32x4;

__device__ __forceinline__ float shfl_sum16(float v) {
  v += __shfl_xor(v, 1, 16);
  v += __shfl_xor(v, 2, 16);
  v += __shfl_xor(v, 4, 16);
  v += __shfl_xor(v, 8, 16);
  return v;
}

// split fp32 -> bf16 hi (chop) + bf16 lo (chop of residual); rel err ~2^-16
__device__ __forceinline__ void split8(const float* f, bf16x8& hi, bf16x8& lo) {
#pragma unroll
  for (int i = 0; i < 8; ++i) {
    unsigned u = __builtin_bit_cast(unsigned, f[i]);
    float hf = __builtin_bit_cast(float, u & 0xFFFF0000u);
    hi[i] = (short)(u >> 16);
    float l = f[i] - hf;
    unsigned ul = __builtin_bit_cast(unsigned, l);
    lo[i] = (short)(ul >> 16);
  }
}

__device__ __forceinline__ void split4(const float* f, s16x4& hi, s16x4& lo) {
#pragma unroll
  for (int i = 0; i < 4; ++i) {
    unsigned u = __builtin_bit_cast(unsigned, f[i]);
    float hf = __builtin_bit_cast(float, u & 0xFFFF0000u);
    hi[i] = (short)(u >> 16);
    float l = f[i] - hf;
    unsigned ul = __builtin_bit_cast(unsigned, l);
    lo[i] = (short)(ul >> 16);
  }
}

// round-to-nearest bf16 (single plane, no lo-compensation)
__device__ __forceinline__ bf16x8 rtn8(const float* f) {
  bf16x8 h;
#pragma unroll
  for (int i = 0; i < 8; ++i) {
    unsigned u = __builtin_bit_cast(unsigned, f[i]);
    u += 0x7FFFu + ((u >> 16) & 1u);
    h[i] = (short)(u >> 16);
  }
  return h;
}

// m214-style plane: 64 rows x 64 shorts (128B rows), byte ^= (row&7)<<4.
__device__ __forceinline__ int planeAddr(int row, int cd) {
  int B = (row << 7) + (cd << 4);
  return B ^ ((row & 7) << 4);
}
__device__ __forceinline__ bf16x8 ldP(const short* __restrict__ P, int row, int cd) {
  return *(const bf16x8*)((const char*)P + planeAddr(row, cd));
}

// in-wave 4x4 transpose among lanes {l, l^16, l^32, l^48}
__device__ __forceinline__ void xpose4(float x[4], int lane) {
  bool p1 = (lane >> 4) & 1;
  float s0 = p1 ? x[0] : x[1], s1 = p1 ? x[2] : x[3];
  float r0 = __shfl_xor(s0, 16, 64), r1 = __shfl_xor(s1, 16, 64);
  if (p1) { x[0] = r0; x[2] = r1; } else { x[1] = r0; x[3] = r1; }
  bool p2 = (lane >> 5) & 1;
  s0 = p2 ? x[0] : x[2]; s1 = p2 ? x[1] : x[3];
  r0 = __shfl_xor(s0, 32, 64); r1 = __shfl_xor(s1, 32, 64);
  if (p2) { x[0] = r0; x[1] = r1; } else { x[2] = r0; x[3] = r1; }
}

// ---------------- Kernel A: landmark means (Q and K) ----------------
__global__ __launch_bounds__(256) void lm_kernel(
    const float* __restrict__ Q, const float* __restrict__ K,
    float* __restrict__ qlm, float* __restrict__ klm) {
  int bh = blockIdx.y; int b = bh >> 4; int h = bh & 15;
  int tid = threadIdx.x;
  int l = blockIdx.x * 4 + (tid >> 6);
  int d = tid & 63;
  const float* qbase = Q + ((size_t)b*NN + (size_t)l*SEG)*CC + h*HD + d;
  const float* kbase = K + ((size_t)b*NN + (size_t)l*SEG)*CC + h*HD + d;
  float sq = 0.f, sk = 0.f;
#pragma unroll 8
  for (int s = 0; s < SEG; ++s) {
    sq += qbase[(size_t)s*CC];
    sk += kbase[(size_t)s*CC];
  }
  qlm[(size_t)bh*4096 + l*64 + d] = sq * (1.0f/(64.0f*8.0f));
  klm[(size_t)bh*4096 + l*64 + d] = sk * (1.0f/64.0f);
}

// ---------------- Kernel B: kernel_3 partials @ V (R7 flow, Kh-only, 4 subs) ----------------
__global__ __launch_bounds__(256, 4) void k3v_kernel(
    const float* __restrict__ K, const float* __restrict__ V,
    const float* __restrict__ qlm,
    float* __restrict__ S3, float* __restrict__ ACC3) {
  __shared__ alignas(16) short KEh[64*64];              // K tile hi plane (8 KB)
  __shared__ alignas(16) short VtH[64*64], VtL[64*64];  // V^T planes (16 KB)
  __shared__ alignas(16) char  Ebuf[16384];             // E fp32, stride 64, XOR swizzle
  const int bh = blockIdx.y, b = bh >> 4, h = bh & 15;
  const int tile = blockIdx.x, tid = threadIdx.x;
  const int wid = tid >> 6, lane = tid & 63;
  const int lr = lane & 15, lg = lane >> 4;
  const int m0 = wid*16 + lg*4;
  const int dV = 4*lr + lg;

  // qlm A-fragments -> registers (split once, chop hi+lo)
  bf16x8 qh[2], ql[2];
#pragma unroll
  for (int ks = 0; ks < 2; ++ks) {
    const float* qp = qlm + (size_t)bh*4096 + (wid*16 + lr)*64 + ks*32 + lg*8;
    float qf[8];
    *(float4*)&qf[0] = *(const float4*)qp;
    *(float4*)&qf[4] = *(const float4*)(qp + 4);
    split8(qf, qh[ks], ql[ks]);
  }

  f32x4 acc2[4];
#pragma unroll
  for (int t = 0; t < 4; ++t) acc2[t] = (f32x4){0.f, 0.f, 0.f, 0.f};
  float srow[4] = {0.f, 0.f, 0.f, 0.f};

  const int rk0 = tid >> 3, ck = tid & 7;
  const int rk1 = rk0 + 32;
  float4 gk[2][2], gv[4];

#define K3V_LOAD(SUB)                                                          \
  {                                                                            \
    const int n0_ = tile*256 + (SUB)*64;                                       \
    const float* kb0 = &K[((size_t)b*NN + n0_ + rk0)*CC + h*HD + ck*8];        \
    const float* kb1 = &K[((size_t)b*NN + n0_ + rk1)*CC + h*HD + ck*8];        \
    gk[0][0] = *(const float4*)kb0;  gk[0][1] = *(const float4*)(kb0 + 4);     \
    gk[1][0] = *(const float4*)kb1;  gk[1][1] = *(const float4*)(kb1 + 4);     \
    _Pragma("unroll")                                                          \
    for (int q = 0; q < 4; ++q) {                                              \
      int f = tid + 256*q;                                                     \
      int r = f >> 4, c4 = (f & 15) << 2;                                      \
      gv[q] = *(const float4*)&V[((size_t)b*NN + n0_ + r)*CC + h*HD + c4];     \
    }                                                                          \
  }

#define K3V_WRITE()                                                            \
  {                                                                            \
    _Pragma("unroll")                                                          \
    for (int q2 = 0; q2 < 2; ++q2) {                                           \
      float kf[8];                                                             \
      *(float4*)&kf[0] = gk[q2][0];                                            \
      *(float4*)&kf[4] = gk[q2][1];                                            \
      bf16x8 khv = rtn8(kf);                                                   \
      int r = q2 ? rk1 : rk0;                                                  \
      *(bf16x8*)((char*)KEh + planeAddr(r, ck)) = khv;                         \
    }                                                                          \
    _Pragma("unroll")                                                          \
    for (int q = 0; q < 4; ++q) {                                              \
      float x[4] = {gv[q].x, gv[q].y, gv[q].z, gv[q].w};                       \
      xpose4(x, lane);                                                         \
      int nb = 16*q + 4*wid;                                                   \
      s16x4 vh, vl; split4(x, vh, vl);                                         \
      int B = (dV << 7) + (nb << 1);                                           \
      B ^= (dV & 7) << 4;                                                      \
      *(s16x4*)((char*)VtH + B) = vh;                                          \
      *(s16x4*)((char*)VtL + B) = vl;                                          \
    }                                                                          \
  }

#define K3V_COMPUTE()                                                          \
  {                                                                            \
    /* GEMM1: z[l][n] over d; B = Kh plane only */                             \
    f32x4 zacc[4];                                                             \
    _Pragma("unroll")                                                          \
    for (int t = 0; t < 4; ++t) zacc[t] = (f32x4){0.f, 0.f, 0.f, 0.f};        \
    _Pragma("unroll")                                                          \
    for (int ks = 0; ks < 2; ++ks) {                                           \
      _Pragma("unroll")                                                        \
      for (int tn = 0; tn < 4; ++tn) {                                         \
        bf16x8 bh_ = ldP(KEh, tn*16 + lr, 4*ks + lg);                          \
        zacc[tn] = __builtin_amdgcn_mfma_f32_16x16x32_bf16(qh[ks], bh_, zacc[tn], 0, 0, 0); \
        zacc[tn] = __builtin_amdgcn_mfma_f32_16x16x32_bf16(ql[ks], bh_, zacc[tn], 0, 0, 0); \
      }                                                                        \
    }                                                                          \
    float ee[4][4];                                                            \
    _Pragma("unroll")                                                          \
    for (int tn = 0; tn < 4; ++tn)                                             \
      _Pragma("unroll")                                                        \
      for (int r = 0; r < 4; ++r) ee[tn][r] = __expf(zacc[tn][r]);             \
    _Pragma("unroll")                                                          \
    for (int r = 0; r < 4; ++r) {                                              \
      float t = ee[0][r] + ee[1][r] + ee[2][r] + ee[3][r];                     \
      srow[r] += shfl_sum16(t);                                                \
    }                                                                          \
    /* E -> own rows (fp32 stride-64, XOR swizzle); no barrier: per-wave strip */ \
    _Pragma("unroll")                                                          \
    for (int tn = 0; tn < 4; ++tn) {                                           \
      _Pragma("unroll")                                                        \
      for (int r = 0; r < 4; ++r) {                                            \
        int row = m0 + r;                                                      \
        int byte = row*256 + (tn*16 + lr)*4;                                   \
        byte ^= (row & 7) << 4;                                                \
        *(float*)(Ebuf + byte) = ee[tn][r];                                    \
      }                                                                        \
    }                                                                          \
    /* GEMM2: acc2[l][d] += E[l][n] * V[n][d] */                               \
    _Pragma("unroll")                                                          \
    for (int ks = 0; ks < 2; ++ks) {                                           \
      int row = wid*16 + lr;                                                   \
      int swz = (row & 7) << 4;                                                \
      int base = row*256 + ks*128 + lg*32;                                     \
      float fa[8];                                                             \
      *(float4*)&fa[0] = *(const float4*)(Ebuf + (base ^ swz));                \
      *(float4*)&fa[4] = *(const float4*)(Ebuf + ((base + 16) ^ swz));         \
      bf16x8 ah, al; split8(fa, ah, al);                                       \
      _Pragma("unroll")                                                        \
      for (int tn = 0; tn < 4; ++tn) {                                         \
        bf16x8 bh_ = ldP(VtH, tn*16 + lr, 4*ks + lg);                          \
        bf16x8 bl_ = ldP(VtL, tn*16 + lr, 4*ks + lg);                          \
        acc2[tn] = __builtin_amdgcn_mfma_f32_16x16x32_bf16(ah, bh_, acc2[tn], 0, 0, 0); \
        acc2[tn] = __builtin_amdgcn_mfma_f32_16x16x32_bf16(ah, bl_, acc2[tn], 0, 0, 0); \
        acc2[tn] = __builtin_amdgcn_mfma_f32_16x16x32_bf16(al, bh_, acc2[tn], 0, 0, 0); \
      }                                                                        \
    }                                                                          \
  }

  K3V_LOAD(0)
  K3V_WRITE()
  __syncthreads();
  K3V_LOAD(1)
  K3V_COMPUTE()
  __syncthreads();
  K3V_WRITE()
  __syncthreads();
  K3V_LOAD(2)
  K3V_COMPUTE()
  __syncthreads();
  K3V_WRITE()
  __syncthreads();
  K3V_LOAD(3)
  K3V_COMPUTE()
  __syncthreads();
  K3V_WRITE()
  __syncthreads();
  K3V_COMPUTE()

  if (lr == 0) {
#pragma unroll
    for (int r = 0; r < 4; ++r)
      atomicAdd(&S3[bh*64 + m0 + r], srow[r]);
  }
#pragma unroll
  for (int tn = 0; tn < 4; ++tn)
#pragma unroll
    for (int r = 0; r < 4; ++r)
      atomicAdd(&ACC3[(size_t)bh*4096 + (m0 + r)*64 + tn*16 + lr], acc2[tn][r]);
}

// ---------------- Kernel C: kernel_2 softmax + Newton-Schulz (16 waves) ----------------
template<bool FUSE, bool HR, bool HC, bool HG>
__device__ __forceinline__ void mm_mfma(
    const float* __restrict__ Arow, const float* __restrict__ Scol,
    float diagc, float scale,
    float* __restrict__ OutRow, float* __restrict__ OutCol, float* __restrict__ OutGlob,
    int wr, int tn, int lane) {
  const int lr = lane & 15, lg = lane >> 4;
  f32x4 acc = (f32x4){0.f, 0.f, 0.f, 0.f};

#pragma unroll
  for (int ks = 0; ks < 2; ++ks) {
    const int kb = ks*32 + lg*8;
    float fa[8];
    const float* ap = Arow + (wr*16 + lr)*MATP + kb;
    *(float4*)&fa[0] = *(const float4*)ap;
    *(float4*)&fa[4] = *(const float4*)(ap + 4);
    bf16x8 ah, al; split8(fa, ah, al);
    float fb[8];
    const float* bp = Scol + (tn*16 + lr)*MATP + kb;
    *(float4*)&fb[0] = *(const float4*)bp;
    *(float4*)&fb[4] = *(const float4*)(bp + 4);
    if (FUSE) {
      int diff = (tn*16 + lr) - kb;
#pragma unroll
      for (int i = 0; i < 8; ++i) fb[i] = (i == diff ? diagc : 0.f) - fb[i];
    }
    bf16x8 bh_, bl_; split8(fb, bh_, bl_);
    acc = __builtin_amdgcn_mfma_f32_16x16x32_bf16(ah, bh_, acc, 0, 0, 0);
    acc = __builtin_amdgcn_mfma_f32_16x16x32_bf16(ah, bl_, acc, 0, 0, 0);
    acc = __builtin_amdgcn_mfma_f32_16x16x32_bf16(al, bh_, acc, 0, 0, 0);
  }
  __syncthreads();
  const int n = tn*16 + lr, m0 = wr*16 + lg*4;
  float v0 = scale*acc[0], v1 = scale*acc[1], v2 = scale*acc[2], v3 = scale*acc[3];
  if (HC) *(float4*)&OutCol[n*MATP + m0] = make_float4(v0, v1, v2, v3);
  if (HR) {
    OutRow[(m0+0)*MATP + n] = v0;
    OutRow[(m0+1)*MATP + n] = v1;
    OutRow[(m0+2)*MATP + n] = v2;
    OutRow[(m0+3)*MATP + n] = v3;
  }
  if (HG) {
    OutGlob[(m0+0)*64 + n] = v0;
    OutGlob[(m0+1)*64 + n] = v1;
    OutGlob[(m0+2)*64 + n] = v2;
    OutGlob[(m0+3)*64 + n] = v3;
  }
  __syncthreads();
}

__global__ __launch_bounds__(1024, 1) void inv_kernel(
    const float* __restrict__ qlm, const float* __restrict__ klm,
    const float* __restrict__ S3, const float* __restrict__ ACC3,
    float* __restrict__ W) {
  extern __shared__ float sm[];
  float* K2row = sm;
  float* Vmrow = sm + 1*MATE;
  float* Vmcol = sm + 2*MATE;
  float* Xrow  = sm + 3*MATE;
  float* Xcol  = sm + 4*MATE;
  float* Ycol  = sm + 5*MATE;
  float* Zcol  = sm + 6*MATE;
  float* rs    = sm + 7*MATE;        // 64 x 4 partials
  float* rinv  = rs + 256;           // 64
  float* red   = rinv + 64;          // 1
  const int bh = blockIdx.x, tid = threadIdx.x;
  const int wid = tid >> 6, lane = tid & 63;
  const int wr = wid & 3, tn = wid >> 2;
  const int lr = lane & 15, lg = lane >> 4;
  const int m0 = wr*16 + lg*4, n = tn*16 + lr;

  {
    int f = tid, r = f >> 4, c4 = (f & 15) << 2;
    *(float4*)&Xrow[r*MATP + c4] = *(const float4*)&qlm[(size_t)bh*4096 + f*4];
    *(float4*)&Xcol[r*MATP + c4] = *(const float4*)&klm[(size_t)bh*4096 + f*4];
  }
  __syncthreads();

  {
    f32x4 zacc = (f32x4){0.f, 0.f, 0.f, 0.f};
#pragma unroll
    for (int ks = 0; ks < 2; ++ks) {
      const int kb = ks*32 + lg*8;
      float fa[8];
      const float* ap = Xrow + (wr*16 + lr)*MATP + kb;
      *(float4*)&fa[0] = *(const float4*)ap;
      *(float4*)&fa[4] = *(const float4*)(ap + 4);
      bf16x8 ah, al; split8(fa, ah, al);
      float fb[8];
      const float* bp = Xcol + (tn*16 + lr)*MATP + kb;
      *(float4*)&fb[0] = *(const float4*)bp;
      *(float4*)&fb[4] = *(const float4*)(bp + 4);
      bf16x8 bh_, bl_; split8(fb, bh_, bl_);
      zacc = __builtin_amdgcn_mfma_f32_16x16x32_bf16(ah, bh_, zacc, 0, 0, 0);
      zacc = __builtin_amdgcn_mfma_f32_16x16x32_bf16(ah, bl_, zacc, 0, 0, 0);
      zacc = __builtin_amdgcn_mfma_f32_16x16x32_bf16(al, bh_, zacc, 0, 0, 0);
    }
    float e[4];
#pragma unroll
    for (int r = 0; r < 4; ++r) e[r] = __expf(zacc[r]);
    float part[4];
#pragma unroll
    for (int r = 0; r < 4; ++r) part[r] = shfl_sum16(e[r]);
    if (lr == 0) {
#pragma unroll
      for (int r = 0; r < 4; ++r) rs[(m0 + r)*4 + tn] = part[r];
    }
    __syncthreads();
    if (tid < 64)
      rinv[tid] = 1.0f / (rs[tid*4] + rs[tid*4+1] + rs[tid*4+2] + rs[tid*4+3]);
    __syncthreads();
#pragma unroll
    for (int r = 0; r < 4; ++r)
      K2row[(m0+r)*MATP + n] = e[r] * rinv[m0 + r];
  }
  __syncthreads();

  if (tid < 64) {
    float c = 0.f;
#pragma unroll 8
    for (int i = 0; i < 64; ++i) c += K2row[i*MATP + tid];
#pragma unroll
    for (int m = 1; m < 64; m <<= 1) c = fmaxf(c, __shfl_xor(c, m, 64));
    if (tid == 0) red[0] = 1.0f / c;
  }
  __syncthreads();
  const float invden = red[0];

  {
    int f = tid, i = f >> 4, c4 = (f & 15) << 2;
    float4 kv = *(const float4*)&K2row[i*MATP + c4];
    kv.x *= invden; kv.y *= invden; kv.z *= invden; kv.w *= invden;
    *(float4*)&Vmcol[i*MATP + c4] = kv;
    Vmrow[(c4+0)*MATP + i] = kv.x;
    Vmrow[(c4+1)*MATP + i] = kv.y;
    Vmrow[(c4+2)*MATP + i] = kv.z;
    Vmrow[(c4+3)*MATP + i] = kv.w;
  }
  __syncthreads();

  for (int it = 0; it < 6; ++it) {
    mm_mfma<false, true,  true,  false>(K2row, Vmcol, 0.f,  1.0f,  Xrow, Xcol, nullptr, wr, tn, lane);
    mm_mfma<true,  false, true,  false>(Xrow,  Xcol,  7.f,  1.0f,  nullptr, Ycol, nullptr, wr, tn, lane);
    mm_mfma<true,  false, true,  false>(Xrow,  Ycol,  15.f, 1.0f,  nullptr, Zcol, nullptr, wr, tn, lane);
    mm_mfma<true,  true,  true,  false>(Vmrow, Zcol,  13.f, 0.25f, Vmrow, Vmcol, nullptr, wr, tn, lane);
  }

  {
    int f = tid, k = f >> 4, c4 = (f & 15) << 2;
    float4 tv = *(const float4*)&ACC3[(size_t)bh*4096 + f*4];
    float ri = 1.0f / S3[bh*64 + k];
    Ycol[(c4+0)*MATP + k] = tv.x * ri;
    Ycol[(c4+1)*MATP + k] = tv.y * ri;
    Ycol[(c4+2)*MATP + k] = tv.z * ri;
    Ycol[(c4+3)*MATP + k] = tv.w * ri;
  }
  __syncthreads();
  mm_mfma<false, false, false, true>(Vmrow, Ycol, 0.f, 1.0f, nullptr, nullptr, W + (size_t)bh*4096, wr, tn, lane);
}

// ---------------- Kernel D: out = softmax(q k_lm^T) @ W (klm JIT, 4/CU) ----------------
__global__ __launch_bounds__(256, 4) void out_kernel(
    const float* __restrict__ Q, const float* __restrict__ klm,
    const float* __restrict__ W, float* __restrict__ Out) {
  __shared__ alignas(16) short WtH[64*64], WtL[64*64];  // W^T planes (16 KB)
  __shared__ alignas(16) float Prow[64*MATP];           // P fp32 (17.4 KB)
  const int bh = blockIdx.y, b = bh >> 4, h = bh & 15;
  const int n0 = blockIdx.x * 64;
  const int tid = threadIdx.x;
  const int wid = tid >> 6, lane = tid & 63;
  const int lr = lane & 15, lg = lane >> 4;
  const int m0 = wid*16 + lg*4;

  const int dW = 4*lr + lg;
#pragma unroll
  for (int q = 0; q < 4; ++q) {
    int f = tid + 256*q;
    int r = f >> 4, c4 = (f & 15) << 2;
    float4 wv = *(const float4*)&W[(size_t)bh*4096 + r*64 + c4];
    float x[4] = {wv.x, wv.y, wv.z, wv.w};
    xpose4(x, lane);
    int nb = 16*q + 4*wid;
    s16x4 wh, wl; split4(x, wh, wl);
    int B = (dW << 7) + (nb << 1);
    B ^= (dW & 7) << 4;
    *(s16x4*)((char*)WtH + B) = wh;
    *(s16x4*)((char*)WtL + B) = wl;
  }

  bf16x8 qh[2], qlo[2];
#pragma unroll
  for (int ks = 0; ks < 2; ++ks) {
    const float* qp = Q + ((size_t)b*NN + n0 + wid*16 + lr)*CC + h*HD + ks*32 + lg*8;
    float qf[8];
    *(float4*)&qf[0] = *(const float4*)qp;
    *(float4*)&qf[4] = *(const float4*)(qp + 4);
#pragma unroll
    for (int i = 0; i < 8; ++i) qf[i] *= 0.125f;
    split8(qf, qh[ks], qlo[ks]);
  }

  f32x4 zacc[4];
#pragma unroll
  for (int t = 0; t < 4; ++t) zacc[t] = (f32x4){0.f, 0.f, 0.f, 0.f};
#pragma unroll
  for (int tn = 0; tn < 4; ++tn) {
    const float* kp = &klm[(size_t)bh*4096 + (tn*16 + lr)*64 + lg*8];
    float4 k00 = *(const float4*)kp;
    float4 k01 = *(const float4*)(kp + 4);
    float4 k10 = *(const float4*)(kp + 32);
    float4 k11 = *(const float4*)(kp + 36);
    float kf[8];
    *(float4*)&kf[0] = k00; *(float4*)&kf[4] = k01;
    bf16x8 b0h, b0l; split8(kf, b0h, b0l);
    *(float4*)&kf[0] = k10; *(float4*)&kf[4] = k11;
    bf16x8 b1h, b1l; split8(kf, b1h, b1l);
    zacc[tn] = __builtin_amdgcn_mfma_f32_16x16x32_bf16(qh[0], b0h, zacc[tn], 0, 0, 0);
    zacc[tn] = __builtin_amdgcn_mfma_f32_16x16x32_bf16(qh[0], b0l, zacc[tn], 0, 0, 0);
    zacc[tn] = __builtin_amdgcn_mfma_f32_16x16x32_bf16(qlo[0], b0h, zacc[tn], 0, 0, 0);
    zacc[tn] = __builtin_amdgcn_mfma_f32_16x16x32_bf16(qh[1], b1h, zacc[tn], 0, 0, 0);
    zacc[tn] = __builtin_amdgcn_mfma_f32_16x16x32_bf16(qh[1], b1l, zacc[tn], 0, 0, 0);
    zacc[tn] = __builtin_amdgcn_mfma_f32_16x16x32_bf16(qlo[1], b1h, zacc[tn], 0, 0, 0);
  }
  float e[4][4];
#pragma unroll
  for (int tn = 0; tn < 4; ++tn)
#pragma unroll
    for (int r = 0; r < 4; ++r) e[tn][r] = __expf(zacc[tn][r]);
#pragma unroll
  for (int r = 0; r < 4; ++r) {
    float t = e[0][r] + e[1][r] + e[2][r] + e[3][r];
    t = shfl_sum16(t);
    float ri = 1.0f / t;
#pragma unroll
    for (int tn = 0; tn < 4; ++tn) e[tn][r] *= ri;
  }
#pragma unroll
  for (int tn = 0; tn < 4; ++tn) {
    const int n = tn*16 + lr;
#pragma unroll
    for (int r = 0; r < 4; ++r) Prow[(m0+r)*MATP + n] = e[tn][r];
  }
  __syncthreads();   // Wt visible

  f32x4 oacc[4];
#pragma unroll
  for (int t = 0; t < 4; ++t) oacc[t] = (f32x4){0.f, 0.f, 0.f, 0.f};
#pragma unroll
  for (int ks = 0; ks < 2; ++ks) {
    float fa[8];
    const float* ap = Prow + (wid*16 + lr)*MATP + ks*32 + lg*8;
    *(float4*)&fa[0] = *(const float4*)ap;
    *(float4*)&fa[4] = *(const float4*)(ap + 4);
    bf16x8 ah, al; split8(fa, ah, al);
#pragma unroll
    for (int tn = 0; tn < 4; ++tn) {
      bf16x8 bh_ = ldP(WtH, tn*16 + lr, 4*ks + lg);
      bf16x8 bl_ = ldP(WtL, tn*16 + lr, 4*ks + lg);
      oacc[tn] = __builtin_amdgcn_mfma_f32_16x16x32_bf16(ah, bh_, oacc[tn], 0, 0, 0);
      oacc[tn] = __builtin_amdgcn_mfma_f32_16x16x32_bf16(ah, bl_, oacc[tn], 0, 0, 0);
      oacc[tn] = __builtin_amdgcn_mfma_f32_16x16x32_bf16(al, bh_, oacc[tn], 0, 0, 0);
    }
  }
#pragma unroll
  for (int tn = 0; tn < 4; ++tn) {
    const int d = tn*16 + lr;
#pragma unroll
    for (int r = 0; r < 4; ++r)
      Out[((size_t)b*NN + n0 + m0 + r)*CC + h*HD + d] = oacc[tn][r];
  }
}

// ---------------- host ----------------
extern "C" void kernel_launch(void* const* d_in, const int* in_sizes, int n_in,
                              void* d_out, int out_size, void* d_ws, size_t ws_size,
                              hipStream_t stream) {
  const float* Q = (const float*)d_in[0];
  const float* K = (const float*)d_in[1];
  const float* V = (const float*)d_in[2];
  float* out = (float*)d_out;
  float* ws  = (float*)d_ws;

  float* qlm  = ws;               // 262144 floats
  float* klm  = ws + 262144;      // 262144
  float* S3   = ws + 524288;      // 4096
  float* ACC3 = ws + 528384;      // 262144
  float* Wm   = ws + 790528;      // 262144

  size_t shC = (size_t)(7*MATE + 384)*sizeof(float);   // ~123 KB
  hipFuncSetAttribute((const void*)inv_kernel,
                      hipFuncAttributeMaxDynamicSharedMemorySize, (int)shC);

  // zero S3 + ACC3 (contiguous) for atomic accumulation
  hipMemsetAsync(S3, 0, (4096 + 262144)*sizeof(float), stream);

  lm_kernel <<<dim3(16, BHN), 256, 0, stream>>>(Q, K, qlm, klm);
  k3v_kernel<<<dim3(16, BHN), 256, 0, stream>>>(K, V, qlm, S3, ACC3);
  inv_kernel<<<dim3(BHN),    1024, shC, stream>>>(qlm, klm, S3, ACC3, Wm);
  out_kernel<<<dim3(64, BHN), 256, 0, stream>>>(Q, klm, Wm, out);
}